// Round 6
// baseline (366.354 us; speedup 1.0000x reference)
//
#include <hip/hip_runtime.h>

// RRSVM — R6 DIAGNOSTIC BUILD (R3 structure, 3x redundant work).
// Each block processes 3 distinct regions (rep-offset bijection mod NB), so
// every region is computed exactly 3 times with identical outputs
// (idempotent; concurrent identical writes are safe). Purpose: make the
// kernel dispatch ~220 us so it tops the rocprof table and exposes
// VALUBusy / FETCH_SIZE / WRITE_SIZE / SQ_LDS_BANK_CONFLICT / Occupancy,
// which fills have masked in every round so far.

#define B_ 16
#define C_ 128
#define H_ 56
#define W_ 56
#define NPIX (B_*C_*H_*W_)   // 6422528
#define BLK 256
#define PXB (BLK * 2)        // 512 pixels per region
#define NB  (NPIX / PXB)     // 12544 regions
#define REP 3

typedef float v4f __attribute__((ext_vector_type(4)));

// Stable descending sort: 9-round odd-even transposition, strict adjacent
// compare (equal keys never swap => matches jnp.argsort(-p) stability).
__device__ __forceinline__ void sort9(float v[9], float id[9]) {
    #pragma unroll
    for (int rnd = 0; rnd < 9; ++rnd) {
        #pragma unroll
        for (int i = (rnd & 1); i + 1 < 9; i += 2) {
            float vi = v[i], vj = v[i + 1];
            float ii = id[i], ij = id[i + 1];
            bool sw = vj > vi;
            v[i]      = sw ? vj : vi;  v[i + 1]  = sw ? vi : vj;
            id[i]     = sw ? ij : ii;  id[i + 1] = sw ? ii : ij;
        }
    }
}

__global__ __launch_bounds__(BLK) void rrsvm_kernel(
    const float* __restrict__ x, const float* __restrict__ s,
    float* __restrict__ out, float* __restrict__ idxout)
{
    __shared__ float lds[PXB * 9];   // 18432 B index staging tile

    const int tid = threadIdx.x;

    #pragma unroll 1
    for (int rep = 0; rep < REP; ++rep) {
        // bijection per rep: every region processed exactly REP times
        int region = blockIdx.x + rep * 4181;
        if (region >= NB) region -= NB;
        if (region >= NB) region -= NB;

        const int pix = (region * BLK + tid) * 2;   // even; pair shares a row
        const int w0  = pix % W_;
        const int t   = pix / W_;
        const int h   = t % H_;
        const int bc  = t / H_;
        const int c   = bc & (C_ - 1);

        const float* sp = s + c * 9;
        float sw9[9];
        #pragma unroll
        for (int r = 0; r < 9; ++r) sw9[r] = sp[r];

        // ---- gather 3 rows x 4 cols, clamped addresses, no branches ----
        const float* img = x + (size_t)bc * (H_ * W_);
        const int r0 = (h > 0)       ? h - 1  : 0;
        const int r2 = (h < H_ - 1)  ? h + 1  : H_ - 1;
        const int c0 = (w0 > 0)      ? w0 - 1 : 0;
        const int c3 = (w0 < W_ - 2) ? w0 + 2 : W_ - 1;
        const float* p0 = img + r0 * W_;
        const float* p1 = img + h  * W_;
        const float* p2 = img + r2 * W_;

        float tap[3][4];
        tap[0][0] = p0[c0]; tap[0][1] = p0[w0]; tap[0][2] = p0[w0 + 1]; tap[0][3] = p0[c3];
        tap[1][0] = p1[c0]; tap[1][1] = p1[w0]; tap[1][2] = p1[w0 + 1]; tap[1][3] = p1[c3];
        tap[2][0] = p2[c0]; tap[2][1] = p2[w0]; tap[2][2] = p2[w0 + 1]; tap[2][3] = p2[c3];

        const bool rv0 = (h > 0), rv2 = (h < H_ - 1);
        const bool cvL = (w0 > 0), cvR = (w0 < W_ - 2);
        tap[0][0] = (rv0 && cvL) ? tap[0][0] : 0.0f;
        tap[0][1] = rv0          ? tap[0][1] : 0.0f;
        tap[0][2] = rv0          ? tap[0][2] : 0.0f;
        tap[0][3] = (rv0 && cvR) ? tap[0][3] : 0.0f;
        tap[1][0] = cvL          ? tap[1][0] : 0.0f;
        tap[1][3] = cvR          ? tap[1][3] : 0.0f;
        tap[2][0] = (rv2 && cvL) ? tap[2][0] : 0.0f;
        tap[2][1] = rv2          ? tap[2][1] : 0.0f;
        tap[2][2] = rv2          ? tap[2][2] : 0.0f;
        tap[2][3] = (rv2 && cvR) ? tap[2][3] : 0.0f;

        float* lbase = lds + tid * 18;
        float2 o;
        {
            float v[9]  = { tap[0][0], tap[0][1], tap[0][2],
                            tap[1][0], tap[1][1], tap[1][2],
                            tap[2][0], tap[2][1], tap[2][2] };
            float id[9] = { 0, 1, 2, 3, 4, 5, 6, 7, 8 };
            sort9(v, id);
            float acc = 0.0f;
            #pragma unroll
            for (int r = 0; r < 9; ++r) acc = fmaf(v[r], sw9[r], acc);
            o.x = acc;
            #pragma unroll
            for (int r = 0; r < 9; ++r) lbase[r] = id[r];
        }
        {
            float v[9]  = { tap[0][1], tap[0][2], tap[0][3],
                            tap[1][1], tap[1][2], tap[1][3],
                            tap[2][1], tap[2][2], tap[2][3] };
            float id[9] = { 0, 1, 2, 3, 4, 5, 6, 7, 8 };
            sort9(v, id);
            float acc = 0.0f;
            #pragma unroll
            for (int r = 0; r < 9; ++r) acc = fmaf(v[r], sw9[r], acc);
            o.y = acc;
            #pragma unroll
            for (int r = 0; r < 9; ++r) lbase[9 + r] = id[r];
        }

        *(float2*)(out + pix) = o;

        __syncthreads();

        v4f* dst = (v4f*)(idxout + (size_t)region * (PXB * 9));
        const v4f* src = (const v4f*)lds;
        __builtin_nontemporal_store(src[tid],        dst + tid);
        __builtin_nontemporal_store(src[tid + 256],  dst + tid + 256);
        __builtin_nontemporal_store(src[tid + 512],  dst + tid + 512);
        __builtin_nontemporal_store(src[tid + 768],  dst + tid + 768);
        if (tid < 128)
            __builtin_nontemporal_store(src[tid + 1024], dst + tid + 1024);

        __syncthreads();   // protect LDS for next rep
    }
}

extern "C" void kernel_launch(void* const* d_in, const int* in_sizes, int n_in,
                              void* d_out, int out_size, void* d_ws, size_t ws_size,
                              hipStream_t stream) {
    const float* x = (const float*)d_in[0];   // [16,128,56,56]
    const float* s = (const float*)d_in[1];   // [128,3,3]
    float* out    = (float*)d_out;            // first NPIX floats
    float* idxout = out + NPIX;               // then NPIX*9 float-encoded ints

    rrsvm_kernel<<<NB, BLK, 0, stream>>>(x, s, out, idxout);
}

// Round 7
// 291.985 us; speedup vs baseline: 1.2547x; 1.2547x over previous
//
#include <hip/hip_runtime.h>

// RRSVM: per (b,c,h,w) take 3x3 zero-padded window, stable-argsort descending,
// out = sum_r v_sorted[r]*s[c,r]; indices emitted as float-encoded ints.
//
// R7: R6 diagnosis = VALU-bound (VALUBusy 71%) on the 36-CE sort network.
// Replace sort with RANK computation (36 ge-compares, +=/-= accumulate,
// ~3 VALU/pair, zero data movement), then:
//   - indices: scatter lds[rank_k] = k  (argsort inversion, LDS-staged
//     writeback unchanged — R4 proved direct strided stores are fatal)
//   - out: acc += v_k * lds_s[sbase + rank_k]  (s staged in LDS, 9-word
//     window -> broadcast reads, conflict-free)
// Tie-break: for pair a<b, ge = v[a]>=v[b] puts a first on ties == stable
// argsort(-p). 4 consecutive regions/block amortize ramp + L3-warm x
// (R6: marginal rep cost 53us vs 72us standalone).

#define B_ 16
#define C_ 128
#define H_ 56
#define W_ 56
#define NPIX (B_*C_*H_*W_)   // 6422528
#define BLK 256
#define PXB (BLK * 2)        // 512 pixels per region
#define NB  (NPIX / PXB)     // 12544 regions
#define RPB 4                // regions per block
#define GRID (NB / RPB)      // 3136 blocks

typedef float v4f __attribute__((ext_vector_type(4)));
typedef float v2f __attribute__((ext_vector_type(2)));

__global__ __launch_bounds__(BLK) void rrsvm_kernel(
    const float* __restrict__ x, const float* __restrict__ s,
    float* __restrict__ out, float* __restrict__ idxout)
{
    __shared__ float lds[PXB * 9];   // 18432 B index staging tile
    __shared__ float lds_s[24];      // <=2 channels x 9 rank weights

    const int tid = threadIdx.x;

    #pragma unroll 1
    for (int rep = 0; rep < RPB; ++rep) {
        const int region = blockIdx.x * RPB + rep;
        const int pixr   = region * PXB;

        // ---- stage s for the (<=2) channels this region touches ----
        const int bcf = pixr / (H_ * W_);
        const int bcl = (pixr + PXB - 1) / (H_ * W_);
        if (tid < 18) {
            const int which = (tid >= 9);
            const int bcx   = which ? bcl : bcf;
            lds_s[tid] = s[(bcx & (C_ - 1)) * 9 + tid - which * 9];
        }
        __syncthreads();   // s staged; prev rep's compute fully done

        const int pix = pixr + tid * 2;     // even; pair shares a row
        const int w0  = pix % W_;
        const int t   = pix / W_;
        const int h   = t % H_;
        const int bc  = t / H_;
        const int sbase = (bc == bcf) ? 0 : 9;

        // ---- gather 3 rows x 4 cols, clamped addresses, no branches ----
        const float* img = x + (size_t)bc * (H_ * W_);
        const int r0 = (h > 0)       ? h - 1  : 0;
        const int r2 = (h < H_ - 1)  ? h + 1  : H_ - 1;
        const int c0 = (w0 > 0)      ? w0 - 1 : 0;
        const int c3 = (w0 < W_ - 2) ? w0 + 2 : W_ - 1;
        const float* p0 = img + r0 * W_;
        const float* p1 = img + h  * W_;
        const float* p2 = img + r2 * W_;

        float tap[3][4];
        tap[0][0] = p0[c0]; tap[0][1] = p0[w0]; tap[0][2] = p0[w0 + 1]; tap[0][3] = p0[c3];
        tap[1][0] = p1[c0]; tap[1][1] = p1[w0]; tap[1][2] = p1[w0 + 1]; tap[1][3] = p1[c3];
        tap[2][0] = p2[c0]; tap[2][1] = p2[w0]; tap[2][2] = p2[w0 + 1]; tap[2][3] = p2[c3];

        const bool rv0 = (h > 0), rv2 = (h < H_ - 1);
        const bool cvL = (w0 > 0), cvR = (w0 < W_ - 2);
        tap[0][0] = (rv0 && cvL) ? tap[0][0] : 0.0f;
        tap[0][1] = rv0          ? tap[0][1] : 0.0f;
        tap[0][2] = rv0          ? tap[0][2] : 0.0f;
        tap[0][3] = (rv0 && cvR) ? tap[0][3] : 0.0f;
        tap[1][0] = cvL          ? tap[1][0] : 0.0f;
        tap[1][3] = cvR          ? tap[1][3] : 0.0f;
        tap[2][0] = (rv2 && cvL) ? tap[2][0] : 0.0f;
        tap[2][1] = rv2          ? tap[2][1] : 0.0f;
        tap[2][2] = rv2          ? tap[2][2] : 0.0f;
        tap[2][3] = (rv2 && cvR) ? tap[2][3] : 0.0f;

        float* lbase = lds + tid * 18;
        v2f o;

        #pragma unroll
        for (int px = 0; px < 2; ++px) {
            const float v[9] = { tap[0][px], tap[0][px+1], tap[0][px+2],
                                 tap[1][px], tap[1][px+1], tap[1][px+2],
                                 tap[2][px], tap[2][px+1], tap[2][px+2] };
            // ---- ranks: rank_k = #{j before k} (stable descending) ----
            int rank[9];
            #pragma unroll
            for (int k = 0; k < 9; ++k) rank[k] = 8 - k;
            #pragma unroll
            for (int a = 0; a < 8; ++a)
                #pragma unroll
                for (int b = a + 1; b < 9; ++b) {
                    const int g = (v[a] >= v[b]);
                    rank[b] += g;
                    rank[a] -= g;
                }
            // ---- scatter indices (argsort inversion) + weighted sum ----
            float acc = 0.0f;
            #pragma unroll
            for (int k = 0; k < 9; ++k) {
                lbase[px * 9 + rank[k]] = (float)k;
                acc = fmaf(v[k], lds_s[sbase + rank[k]], acc);
            }
            if (px == 0) o.x = acc; else o.y = acc;
        }

        // out store: float2, 8B-aligned (pix even), write-once -> NT
        __builtin_nontemporal_store(o, (v2f*)(out + pix));

        __syncthreads();   // all scatter writes visible

        // ---- coalesced NT float4 writeback: 512*9 = 2304 f4 = 4.5*512 ----
        v4f* dst = (v4f*)(idxout + (size_t)region * (PXB * 9));
        const v4f* src = (const v4f*)lds;
        __builtin_nontemporal_store(src[tid],        dst + tid);
        __builtin_nontemporal_store(src[tid + 256],  dst + tid + 256);
        __builtin_nontemporal_store(src[tid + 512],  dst + tid + 512);
        __builtin_nontemporal_store(src[tid + 768],  dst + tid + 768);
        if (tid < 128)
            __builtin_nontemporal_store(src[tid + 1024], dst + tid + 1024);
    }
}

extern "C" void kernel_launch(void* const* d_in, const int* in_sizes, int n_in,
                              void* d_out, int out_size, void* d_ws, size_t ws_size,
                              hipStream_t stream) {
    const float* x = (const float*)d_in[0];   // [16,128,56,56]
    const float* s = (const float*)d_in[1];   // [128,3,3]
    float* out    = (float*)d_out;            // first NPIX floats
    float* idxout = out + NPIX;               // then NPIX*9 float-encoded ints

    rrsvm_kernel<<<GRID, BLK, 0, stream>>>(x, s, out, idxout);
}

// Round 8
// 271.039 us; speedup vs baseline: 1.3517x; 1.0773x over previous
//
#include <hip/hip_runtime.h>

// RRSVM: per (b,c,h,w) take 3x3 zero-padded window, stable-argsort descending,
// out = sum_r v_sorted[r]*s[c,r]; indices emitted as float-encoded ints.
//
// R8: 4 px/thread (contiguous quad), rank-based core (R7-verified tie-break),
// and U8 LDS staging of the index tile: 1024px*9 = 9216 B (vs 36.9 KB f32),
// keeping 8 blocks/CU (R5 showed 16 waves/CU is fatal). Writeback reads one
// dword (=4 idx bytes) per f4 store at dword tid+256k -> conflict-free LDS,
// perfectly lane-contiguous NT float4 global stores (R4 lesson).
// Gather: 3 float4 + 6 edge scalars per 4 px. s staged in LDS (<=2 channels
// per 1024-px region), FMA reads s[rank] dynamically (9-word broadcast window).

#define B_ 16
#define C_ 128
#define H_ 56
#define W_ 56
#define HW (H_*W_)           // 3136
#define NPIX (B_*C_*H_*W_)   // 6422528
#define BLK 256
#define PXT 4
#define PXB (BLK * PXT)      // 1024 pixels per block region
#define GRID (NPIX / PXB)    // 6272

typedef float v4f __attribute__((ext_vector_type(4)));

__global__ __launch_bounds__(BLK) void rrsvm_kernel(
    const float* __restrict__ x, const float* __restrict__ s,
    float* __restrict__ out, float* __restrict__ idxout)
{
    __shared__ unsigned char lds_idx[PXB * 9];   // 9216 B, byte-staged indices
    __shared__ float lds_s[24];                  // <=2 channels x 9 weights

    const int tid  = threadIdx.x;
    const int pixr = blockIdx.x * PXB;
    const int pix0 = pixr + tid * PXT;   // contiguous quad, 16B-aligned
    const int w0   = pix0 % W_;          // in {0,4,...,52} (quad shares a row)
    const int t    = pix0 / W_;
    const int h    = t % H_;
    const int bc   = t / H_;

    // ---- stage s for the (<=2) channels this region touches ----
    const int bcf = pixr / HW;
    const int bcl = (pixr + PXB - 1) / HW;
    if (tid < 18) {
        const int which = (tid >= 9);
        const int bcx   = which ? bcl : bcf;
        lds_s[tid] = s[(bcx & (C_ - 1)) * 9 + tid - which * 9];
    }
    const int sbase = (bc == bcf) ? 0 : 9;

    // ---- gather 3 rows x 6 cols: float4 middle + 2 clamped edge scalars ----
    const float* img = x + (size_t)bc * HW;
    const int r0 = (h > 0)      ? h - 1 : 0;
    const int r2 = (h < H_ - 1) ? h + 1 : H_ - 1;
    const int cl = (w0 > 0)        ? w0 - 1 : 0;
    const int cr = (w0 < W_ - PXT) ? w0 + 4 : W_ - 1;
    const float* p0 = img + r0 * W_;
    const float* p1 = img + h  * W_;
    const float* p2 = img + r2 * W_;

    float T[3][6];
    {
        v4f m0 = *(const v4f*)(p0 + w0);
        v4f m1 = *(const v4f*)(p1 + w0);
        v4f m2 = *(const v4f*)(p2 + w0);
        T[0][0] = p0[cl]; T[0][1] = m0.x; T[0][2] = m0.y; T[0][3] = m0.z; T[0][4] = m0.w; T[0][5] = p0[cr];
        T[1][0] = p1[cl]; T[1][1] = m1.x; T[1][2] = m1.y; T[1][3] = m1.z; T[1][4] = m1.w; T[1][5] = p1[cr];
        T[2][0] = p2[cl]; T[2][1] = m2.x; T[2][2] = m2.y; T[2][3] = m2.z; T[2][4] = m2.w; T[2][5] = p2[cr];
    }
    const bool rv0 = (h > 0), rv2 = (h < H_ - 1);
    const bool cvL = (w0 > 0), cvR = (w0 < W_ - PXT);
    #pragma unroll
    for (int j = 0; j < 6; ++j) {
        T[0][j] = rv0 ? T[0][j] : 0.0f;
        T[2][j] = rv2 ? T[2][j] : 0.0f;
    }
    T[0][0] = cvL ? T[0][0] : 0.0f;
    T[1][0] = cvL ? T[1][0] : 0.0f;
    T[2][0] = cvL ? T[2][0] : 0.0f;
    T[0][5] = cvR ? T[0][5] : 0.0f;
    T[1][5] = cvR ? T[1][5] : 0.0f;
    T[2][5] = cvR ? T[2][5] : 0.0f;

    __syncthreads();   // lds_s visible

    float oacc[PXT];
    #pragma unroll
    for (int px = 0; px < PXT; ++px) {
        const float v[9] = { T[0][px], T[0][px+1], T[0][px+2],
                             T[1][px], T[1][px+1], T[1][px+2],
                             T[2][px], T[2][px+1], T[2][px+2] };
        // rank_k = #elements placed before k in stable descending order
        int rank[9];
        #pragma unroll
        for (int k = 0; k < 9; ++k) rank[k] = 8 - k;
        #pragma unroll
        for (int a = 0; a < 8; ++a)
            #pragma unroll
            for (int b = a + 1; b < 9; ++b) {
                const int g = (v[a] >= v[b]);   // CSE'd across adjacent windows
                rank[b] += g;
                rank[a] -= g;
            }
        // scatter idx byte (argsort inversion) + weighted sum via s[rank]
        const int base_b = tid * 36 + px * 9;
        float acc = 0.0f;
        #pragma unroll
        for (int k = 0; k < 9; ++k) {
            lds_idx[base_b + rank[k]] = (unsigned char)k;
            acc = fmaf(v[k], lds_s[sbase + rank[k]], acc);
        }
        oacc[px] = acc;
    }
    v4f o; o.x = oacc[0]; o.y = oacc[1]; o.z = oacc[2]; o.w = oacc[3];
    __builtin_nontemporal_store(o, (v4f*)(out + pix0));

    __syncthreads();   // all idx bytes staged

    // ---- writeback: dword (tid+256k) = 4 idx bytes -> one f4 store ----
    const unsigned int* lu = (const unsigned int*)lds_idx;
    v4f* dst = (v4f*)(idxout + (size_t)pixr * 9);
    #pragma unroll
    for (int k = 0; k < 9; ++k) {
        const unsigned int u = lu[tid + 256 * k];
        v4f f;
        f.x = (float)( u        & 0xff);
        f.y = (float)((u >>  8) & 0xff);
        f.z = (float)((u >> 16) & 0xff);
        f.w = (float)((u >> 24)       );
        __builtin_nontemporal_store(f, dst + tid + 256 * k);
    }
}

extern "C" void kernel_launch(void* const* d_in, const int* in_sizes, int n_in,
                              void* d_out, int out_size, void* d_ws, size_t ws_size,
                              hipStream_t stream) {
    const float* x = (const float*)d_in[0];   // [16,128,56,56]
    const float* s = (const float*)d_in[1];   // [128,3,3]
    float* out    = (float*)d_out;            // first NPIX floats
    float* idxout = out + NPIX;               // then NPIX*9 float-encoded ints

    rrsvm_kernel<<<GRID, BLK, 0, stream>>>(x, s, out, idxout);
}